// Round 10
// baseline (721.874 us; speedup 1.0000x reference)
//
#include <hip/hip_runtime.h>

// NCC dual-force 3D, 256^3 fp32 — R11 ABLATION (distinct kernel names!).
// Wall is 121+-1us across 6 structurally different kernels; data-side
// changes (traffic -40%, packed VALU, prefetch) all flat; ADDING body size
// (R9 halo +~20%) costs exactly proportional time (+21%). Surviving theory:
// INSTRUCTION-FETCH bound — 8x-unrolled body ~25-30KB vs 32KB shared I$,
// staggered waves thrash; time ~ code-bytes-fetched/iter. Predicts chunk16
// neutral (2x body x 1/2 blocks), halo +21%, packed neutral (scalarized ->
// same count). This round A/Bs it against residency & parallelism:
//  1 ncc_ctl    R10 exact (cold-eater control)        pred ~121us
//  2 ncc_rolled unroll-1 loop, named-reg ring, ~3.5KB pred 75-95us if I$
//  3 ncc_by4    BY=4 256-thr blocks                   pred 65-80us if WG-slots
//  4 ncc_cz4    CHUNK_Z=4, 2x blocks (+20% work)      pred 75-90us if parallelism
//  5 ncc_ctl    -> FINAL OUTPUT (correctness: full overwrite, absmax 80)
// Spill tripwire per-variant: WRITE_SIZE ~197MB. FP op order unchanged.

constexpr int DIM     = 256;
constexpr int PLANE   = DIM * DIM;
constexpr int NVOX    = DIM * DIM * DIM;
constexpr float EPSF  = 1e-6f;
constexpr int NXCD  = 8;

typedef float  nvec4  __attribute__((ext_vector_type(4)));
typedef int    nivec4 __attribute__((ext_vector_type(4)));
typedef float  v2f    __attribute__((ext_vector_type(2)));

struct f4p { v2f lo, hi; };            // 4 floats as two packed pairs

__device__ __forceinline__ v2f lo2(nvec4 v){ return __builtin_shufflevector(v, v, 0, 1); }
__device__ __forceinline__ v2f hi2(nvec4 v){ return __builtin_shufflevector(v, v, 2, 3); }
__device__ __forceinline__ f4p mkp(nvec4 v){ f4p r; r.lo = lo2(v); r.hi = hi2(v); return r; }

__device__ __forceinline__ float shlz(float v) {
    float r = __shfl_up(v, 1);
    return (threadIdx.x == 0) ? 0.f : r;
}
__device__ __forceinline__ float shrz(float v) {
    float r = __shfl_down(v, 1);
    return (threadIdx.x == 63) ? 0.f : r;
}

// packed helpers — per-element expression shape identical to scalar originals
__device__ __forceinline__ f4p add3p(const f4p& a, const f4p& b, const f4p& c) {
    f4p r; r.lo = a.lo + b.lo + c.lo; r.hi = a.hi + b.hi + c.hi; return r;
}
__device__ __forceinline__ f4p add2p(const f4p& a, const f4p& b) {
    f4p r; r.lo = a.lo + b.lo; r.hi = a.hi + b.hi; return r;
}
__device__ __forceinline__ f4p prod3p(const f4p& a, const f4p& b, const f4p& c,
                                      const f4p& d, const f4p& e, const f4p& f) {
    f4p r;
    r.lo = a.lo*b.lo + c.lo*d.lo + e.lo*f.lo;
    r.hi = a.hi*b.hi + c.hi*d.hi + e.hi*f.hi;
    return r;
}
__device__ __forceinline__ f4p sub4p(const f4p& a, const f4p& b) {
    f4p r; r.lo = a.lo - b.lo; r.hi = a.hi - b.hi; return r;
}
__device__ __forceinline__ f4p scl4p(const f4p& a, float s) {
    f4p r; r.lo = a.lo * s; r.hi = a.hi * s; return r;
}
__device__ __forceinline__ f4p xsum3p(const f4p& c, float l, float r) {
    const float c0 = c.lo.x, c1 = c.lo.y, c2 = c.hi.x, c3 = c.hi.y;
    v2f A = {l,  c0}, B = {c0, c1}, C = {c1, c2};
    v2f D = {c1, c2}, E = {c2, c3}, F = {c3, r};
    f4p o; o.lo = A + B + C; o.hi = D + E + F; return o;
}
__device__ __forceinline__ void ntstore4p(float* p, v2f lo, v2f hi) {
    nvec4 t = __builtin_shufflevector(lo, hi, 0, 1, 2, 3);
    __builtin_nontemporal_store(t, (nvec4*)p);
}

// packed pointwise NCC-force: 2 voxels per call; op-for-op the scalar pw1.
__device__ __forceinline__ void pw1p(
    v2f sum_m, v2f sum_f, v2f sum_mm, v2f sum_ff, v2f sum_mf,
    v2f mA, v2f mB, v2f mN,
    v2f fA, v2f fB, v2f fN,
    int zflag,
    v2f gx_m, v2f gy_m, v2f gx_f, v2f gy_f,
    int km0, int km1, int kf0, int kf1,
    v2f& o0, v2f& o1, v2f& o2)
{
    v2f mmean = sum_m / 27.0f;
    v2f fmean = sum_f / 27.0f;
    v2f var_m = sum_mm - 2.f*mmean*sum_m + 27.f*mmean*mmean;
    v2f var_f = sum_ff - 2.f*fmean*sum_f + 27.f*fmean*fmean;
    v2f var_mf = var_m * var_f;
    v2f cross = sum_mf - fmean*sum_m - mmean*sum_f + 27.f*mmean*fmean;
    v2f mmc = mB - mmean, fmc = fB - fmean;
    v2f factor = 2.f * cross / (var_mf + EPSF)
                 * (mmc - cross / (var_f*fmc + EPSF));
    v2f gzm = (zflag < 0) ? (mN - mB) : ((zflag > 0) ? (mB - mA) : 0.5f*(mN - mA));
    v2f gzf = (zflag < 0) ? (fN - fB) : ((zflag > 0) ? (fB - fA) : 0.5f*(fN - fA));
    v2f wm = { km0 ? 1.f : 0.f, km1 ? 1.f : 0.f };
    v2f wf = { kf0 ? 1.f : 0.f, kf1 ? 1.f : 0.f };
    v2f tgz = 0.5f*(gzm *wm + gzf *wf);
    v2f tgy = 0.5f*(gy_m*wm + gy_f*wf);
    v2f tgx = 0.5f*(gx_m*wm + gx_f*wf);
    o0 = -factor * tgz;
    o1 = -factor * tgy;
    o2 = -factor * tgx;
}

struct RawP { nvec4 mU, mC, mD, fU, fC, fD; };

__device__ __forceinline__ RawP load_planes(const float* __restrict__ M,
                                            const float* __restrict__ F,
                                            int zl, size_t yoff, bool yUok, bool yDok)
{
    const nvec4 z4 = {0.f, 0.f, 0.f, 0.f};
    RawP r; r.mU = z4; r.mC = z4; r.mD = z4; r.fU = z4; r.fC = z4; r.fD = z4;
    if ((unsigned)zl < (unsigned)DIM) {
        const float* pm = M + (size_t)zl * PLANE + yoff;
        const float* pf = F + (size_t)zl * PLANE + yoff;
        r.mC = *(const nvec4*)pm;  r.fC = *(const nvec4*)pf;
        if (yUok) { r.mU = *(const nvec4*)(pm - DIM); r.fU = *(const nvec4*)(pf - DIM); }
        if (yDok) { r.mD = *(const nvec4*)(pm + DIM); r.fD = *(const nvec4*)(pf + DIM); }
    }
    return r;
}

// ingest compute half — writes center planes via refs (no arrays needed)
__device__ __forceinline__ void ingest_p(
    const RawP& r, int y,
    f4p& mcO, f4p& fcO,
    f4p& Pm, f4p& Pf, f4p& Pmm, f4p& Pff, f4p& Pmf,
    f4p& gxm, f4p& gym, f4p& gxf, f4p& gyf)
{
    const f4p mU = mkp(r.mU), mC = mkp(r.mC), mD = mkp(r.mD);
    const f4p fU = mkp(r.fU), fC = mkp(r.fC), fD = mkp(r.fD);
    f4p Cm  = add3p(mU, mC, mD);
    f4p Cf  = add3p(fU, fC, fD);
    f4p Cmm = prod3p(mU, mU, mC, mC, mD, mD);
    f4p Cff = prod3p(fU, fU, fC, fC, fD, fD);
    f4p Cmf = prod3p(mU, fU, mC, fC, mD, fD);
    Pm  = xsum3p(Cm,  shlz(Cm.hi.y),  shrz(Cm.lo.x));
    Pf  = xsum3p(Cf,  shlz(Cf.hi.y),  shrz(Cf.lo.x));
    Pmm = xsum3p(Cmm, shlz(Cmm.hi.y), shrz(Cmm.lo.x));
    Pff = xsum3p(Cff, shlz(Cff.hi.y), shrz(Cff.lo.x));
    Pmf = xsum3p(Cmf, shlz(Cmf.hi.y), shrz(Cmf.lo.x));
    mcO = mC; fcO = fC;
    const float m0 = mC.lo.x, m1 = mC.lo.y, m2 = mC.hi.x, m3 = mC.hi.y;
    const float f0 = fC.lo.x, f1 = fC.lo.y, f2 = fC.hi.x, f3 = fC.hi.y;
    float mL = shlz(m3), mR = shrz(m0);
    float fL = shlz(f3), fR = shrz(f0);
    gxm.lo = v2f{ (threadIdx.x == 0)  ? (m1 - m0) : 0.5f*(m1 - mL), 0.5f*(m2 - m0) };
    gxm.hi = v2f{ 0.5f*(m3 - m1), (threadIdx.x == 63) ? (m3 - m2) : 0.5f*(mR - m2) };
    gxf.lo = v2f{ (threadIdx.x == 0)  ? (f1 - f0) : 0.5f*(f1 - fL), 0.5f*(f2 - f0) };
    gxf.hi = v2f{ 0.5f*(f3 - f1), (threadIdx.x == 63) ? (f3 - f2) : 0.5f*(fR - f2) };
    gym = (y == 0) ? sub4p(mD, mC) : (y == DIM-1) ? sub4p(mC, mU) : scl4p(sub4p(mD, mU), 0.5f);
    gyf = (y == 0) ? sub4p(fD, fC) : (y == DIM-1) ? sub4p(fC, fU) : scl4p(sub4p(fD, fU), 0.5f);
}

// per-iteration epilogue shared by both bodies (always inlined)
__device__ __forceinline__ void step_out(
    const f4p& sm, const f4p& sf, const f4p& smm, const f4p& sff, const f4p& smf,
    const f4p& mcA, const f4p& mcB, const f4p& mcC,
    const f4p& fcA, const f4p& fcB, const f4p& fcC,
    int zflag, const f4p& gxm_p, const f4p& gym_p, const f4p& gxf_p, const f4p& gyf_p,
    const nivec4& km, const nivec4& kf, float* out, size_t idx)
{
    v2f o0l, o1l, o2l, o0h, o1h, o2h;
    pw1p(sm.lo, sf.lo, smm.lo, sff.lo, smf.lo,
         mcA.lo, mcB.lo, mcC.lo, fcA.lo, fcB.lo, fcC.lo, zflag,
         gxm_p.lo, gym_p.lo, gxf_p.lo, gyf_p.lo,
         km.x, km.y, kf.x, kf.y, o0l, o1l, o2l);
    pw1p(sm.hi, sf.hi, smm.hi, sff.hi, smf.hi,
         mcA.hi, mcB.hi, mcC.hi, fcA.hi, fcB.hi, fcC.hi, zflag,
         gxm_p.hi, gym_p.hi, gxf_p.hi, gyf_p.hi,
         km.z, km.w, kf.z, kf.w, o0h, o1h, o2h);
    ntstore4p(out + idx,            o0l, o0h);
    ntstore4p(out + NVOX + idx,     o1l, o1h);
    ntstore4p(out + 2 * NVOX + idx, o2l, o2h);
}

// ---------------- unrolled body (R10 structure), CZ/BYT templated ----------
template<int CZ, int BYT>
__device__ __forceinline__ void body_unrolled(
    const float* __restrict__ M, const float* __restrict__ F,
    const int* __restrict__ maskM, const int* __restrict__ maskF,
    float* __restrict__ out)
{
    constexpr int NBY_ = DIM / BYT;
    constexpr int NBZ_ = DIM / CZ;
    constexpr int NWG_ = NBY_ * NBZ_;
    constexpr int CHX_ = NWG_ / NXCD;

    const int wg  = (int)blockIdx.x;
    const int swz = (wg & (NXCD - 1)) * CHX_ + (wg >> 3);
    const int by  = swz % NBY_;
    const int bz  = swz / NBY_;

    const int y  = by * BYT + threadIdx.y;
    const int z0 = bz * CZ;
    const int xb = threadIdx.x * 4;
    const bool yUok = (y > 0), yDok = (y < DIM - 1);
    const size_t yoff = (size_t)y * DIM + xb;

    f4p mc[3], fc[3];
    f4p gxm_p, gym_p, gxf_p, gyf_p;

    nivec4 km = __builtin_nontemporal_load((const nivec4*)(maskM + (size_t)z0 * PLANE + yoff));
    nivec4 kf = __builtin_nontemporal_load((const nivec4*)(maskF + (size_t)z0 * PLANE + yoff));
    RawP r0 = load_planes(M, F, z0 - 1, yoff, yUok, yDok);
    RawP r1 = load_planes(M, F, z0,     yoff, yUok, yDok);
    RawP rN = load_planes(M, F, z0 + 1, yoff, yUok, yDok);

    f4p SAm, SAf, SAmm, SAff, SAmf, SBm, SBf, SBmm, SBff, SBmf;
    {
        f4p P0m, P0f, P0mm, P0ff, P0mf, d0, d1, d2, d3;
        ingest_p(r0, y, mc[0], fc[0], P0m, P0f, P0mm, P0ff, P0mf, d0, d1, d2, d3);
        f4p P1m, P1f, P1mm, P1ff, P1mf;
        ingest_p(r1, y, mc[1], fc[1], P1m, P1f, P1mm, P1ff, P1mf,
                 gxm_p, gym_p, gxf_p, gyf_p);
        SAm  = add2p(P0m,  P1m );  SBm  = P1m;
        SAf  = add2p(P0f,  P1f );  SBf  = P1f;
        SAmm = add2p(P0mm, P1mm);  SBmm = P1mm;
        SAff = add2p(P0ff, P1ff);  SBff = P1ff;
        SAmf = add2p(P0mf, P1mf);  SBmf = P1mf;
    }

    #pragma unroll
    for (int s = 2; s < CZ + 2; ++s) {
        const int i2 = s % 3, i1 = (s + 2) % 3, i0 = (s + 1) % 3;
        const int zo = z0 + s - 2;
        const int zflag = (zo == 0) ? -1 : ((zo == DIM - 1) ? 1 : 0);
        const size_t idx = (size_t)zo * PLANE + yoff;

        f4p gxm, gym, gxf, gyf;
        f4p Pm2, Pf2, Pmm2, Pff2, Pmf2;
        ingest_p(rN, y, mc[i2], fc[i2], Pm2, Pf2, Pmm2, Pff2, Pmf2,
                 gxm, gym, gxf, gyf);

        nivec4 kmT, kfT;
        if (s < CZ + 1) {
            rN  = load_planes(M, F, z0 + s, yoff, yUok, yDok);
            kmT = __builtin_nontemporal_load((const nivec4*)(maskM + idx + PLANE));
            kfT = __builtin_nontemporal_load((const nivec4*)(maskF + idx + PLANE));
        }

        f4p sm  = add2p(SAm,  Pm2);
        f4p sf  = add2p(SAf,  Pf2);
        f4p smm = add2p(SAmm, Pmm2);
        f4p sff = add2p(SAff, Pff2);
        f4p smf = add2p(SAmf, Pmf2);

        step_out(sm, sf, smm, sff, smf, mc[i0], mc[i1], mc[i2],
                 fc[i0], fc[i1], fc[i2], zflag, gxm_p, gym_p, gxf_p, gyf_p,
                 km, kf, out, idx);

        SAm  = add2p(SBm,  Pm2 );  SBm  = Pm2;
        SAf  = add2p(SBf,  Pf2 );  SBf  = Pf2;
        SAmm = add2p(SBmm, Pmm2);  SBmm = Pmm2;
        SAff = add2p(SBff, Pff2);  SBff = Pff2;
        SAmf = add2p(SBmf, Pmf2);  SBmf = Pmf2;
        gxm_p = gxm; gym_p = gym; gxf_p = gxf; gyf_p = gyf;
        if (s < CZ + 1) { km = kmT; kf = kfT; }
    }
}

// ---------------- rolled body: unroll-1, named-register ring -------------
__device__ __forceinline__ void body_rolled(
    const float* __restrict__ M, const float* __restrict__ F,
    const int* __restrict__ maskM, const int* __restrict__ maskF,
    float* __restrict__ out)
{
    constexpr int CZ = 8, BYT = 2;
    constexpr int NBY_ = DIM / BYT;
    constexpr int NBZ_ = DIM / CZ;
    constexpr int NWG_ = NBY_ * NBZ_;
    constexpr int CHX_ = NWG_ / NXCD;

    const int wg  = (int)blockIdx.x;
    const int swz = (wg & (NXCD - 1)) * CHX_ + (wg >> 3);
    const int by  = swz % NBY_;
    const int bz  = swz / NBY_;

    const int y  = by * BYT + threadIdx.y;
    const int z0 = bz * CZ;
    const int xb = threadIdx.x * 4;
    const bool yUok = (y > 0), yDok = (y < DIM - 1);
    const size_t yoff = (size_t)y * DIM + xb;

    f4p mcA, mcB, fcA, fcB;              // center planes zo-1, zo (named, no arrays)
    f4p gxm_p, gym_p, gxf_p, gyf_p;

    nivec4 km = __builtin_nontemporal_load((const nivec4*)(maskM + (size_t)z0 * PLANE + yoff));
    nivec4 kf = __builtin_nontemporal_load((const nivec4*)(maskF + (size_t)z0 * PLANE + yoff));
    RawP r0 = load_planes(M, F, z0 - 1, yoff, yUok, yDok);
    RawP r1 = load_planes(M, F, z0,     yoff, yUok, yDok);
    RawP rN = load_planes(M, F, z0 + 1, yoff, yUok, yDok);

    f4p SAm, SAf, SAmm, SAff, SAmf, SBm, SBf, SBmm, SBff, SBmf;
    {
        f4p P0m, P0f, P0mm, P0ff, P0mf, d0, d1, d2, d3;
        ingest_p(r0, y, mcA, fcA, P0m, P0f, P0mm, P0ff, P0mf, d0, d1, d2, d3);
        f4p P1m, P1f, P1mm, P1ff, P1mf;
        ingest_p(r1, y, mcB, fcB, P1m, P1f, P1mm, P1ff, P1mf,
                 gxm_p, gym_p, gxf_p, gyf_p);
        SAm  = add2p(P0m,  P1m );  SBm  = P1m;
        SAf  = add2p(P0f,  P1f );  SBf  = P1f;
        SAmm = add2p(P0mm, P1mm);  SBmm = P1mm;
        SAff = add2p(P0ff, P1ff);  SBff = P1ff;
        SAmf = add2p(P0mf, P1mf);  SBmf = P1mf;
    }

    #pragma unroll 1
    for (int s = 2; s < CZ + 2; ++s) {
        const int zo = z0 + s - 2;
        const int zflag = (zo == 0) ? -1 : ((zo == DIM - 1) ? 1 : 0);
        const size_t idx = (size_t)zo * PLANE + yoff;

        f4p mcC, fcC, gxm, gym, gxf, gyf;
        f4p Pm2, Pf2, Pmm2, Pff2, Pmf2;
        ingest_p(rN, y, mcC, fcC, Pm2, Pf2, Pmm2, Pff2, Pmf2,
                 gxm, gym, gxf, gyf);

        nivec4 kmT, kfT;
        if (s < CZ + 1) {
            rN  = load_planes(M, F, z0 + s, yoff, yUok, yDok);
            kmT = __builtin_nontemporal_load((const nivec4*)(maskM + idx + PLANE));
            kfT = __builtin_nontemporal_load((const nivec4*)(maskF + idx + PLANE));
        }

        f4p sm  = add2p(SAm,  Pm2);
        f4p sf  = add2p(SAf,  Pf2);
        f4p smm = add2p(SAmm, Pmm2);
        f4p sff = add2p(SAff, Pff2);
        f4p smf = add2p(SAmf, Pmf2);

        step_out(sm, sf, smm, sff, smf, mcA, mcB, mcC,
                 fcA, fcB, fcC, zflag, gxm_p, gym_p, gxf_p, gyf_p,
                 km, kf, out, idx);

        SAm  = add2p(SBm,  Pm2 );  SBm  = Pm2;
        SAf  = add2p(SBf,  Pf2 );  SBf  = Pf2;
        SAmm = add2p(SBmm, Pmm2);  SBmm = Pmm2;
        SAff = add2p(SBff, Pff2);  SBff = Pff2;
        SAmf = add2p(SBmf, Pmf2);  SBmf = Pmf2;
        mcA = mcB; mcB = mcC; fcA = fcB; fcB = fcC;   // ring rotation (v_mov)
        gxm_p = gxm; gym_p = gym; gxf_p = gxf; gyf_p = gyf;
        if (s < CZ + 1) { km = kmT; kf = kfT; }
    }
}

// ---------------- distinct-name wrappers (profiler separability) ----------
__global__ __launch_bounds__(128) void ncc_ctl(
    const float* __restrict__ M, const float* __restrict__ F,
    const int* __restrict__ mm, const int* __restrict__ fm, float* __restrict__ out)
{ body_unrolled<8, 2>(M, F, mm, fm, out); }

__global__ __launch_bounds__(128) void ncc_rolled(
    const float* __restrict__ M, const float* __restrict__ F,
    const int* __restrict__ mm, const int* __restrict__ fm, float* __restrict__ out)
{ body_rolled(M, F, mm, fm, out); }

__global__ __launch_bounds__(256) void ncc_by4(
    const float* __restrict__ M, const float* __restrict__ F,
    const int* __restrict__ mm, const int* __restrict__ fm, float* __restrict__ out)
{ body_unrolled<8, 4>(M, F, mm, fm, out); }

__global__ __launch_bounds__(128) void ncc_cz4(
    const float* __restrict__ M, const float* __restrict__ F,
    const int* __restrict__ mm, const int* __restrict__ fm, float* __restrict__ out)
{ body_unrolled<4, 2>(M, F, mm, fm, out); }

extern "C" void kernel_launch(void* const* d_in, const int* in_sizes, int n_in,
                              void* d_out, int out_size, void* d_ws, size_t ws_size,
                              hipStream_t stream) {
    const float* M  = (const float*)d_in[0];
    const float* F  = (const float*)d_in[1];
    const int* mm   = (const int*)d_in[2];
    const int* fm   = (const int*)d_in[3];
    float* out      = (float*)d_out;

    // ABLATION: ctl (cold) -> rolled -> by4 -> cz4 -> ctl (FINAL OUTPUT)
    hipLaunchKernelGGL(ncc_ctl,    dim3(4096), dim3(64, 2, 1), 0, stream, M, F, mm, fm, out);
    hipLaunchKernelGGL(ncc_rolled, dim3(4096), dim3(64, 2, 1), 0, stream, M, F, mm, fm, out);
    hipLaunchKernelGGL(ncc_by4,    dim3(2048), dim3(64, 4, 1), 0, stream, M, F, mm, fm, out);
    hipLaunchKernelGGL(ncc_cz4,    dim3(8192), dim3(64, 2, 1), 0, stream, M, F, mm, fm, out);
    hipLaunchKernelGGL(ncc_ctl,    dim3(4096), dim3(64, 2, 1), 0, stream, M, F, mm, fm, out);
}